// Round 4
// baseline (4790.980 us; speedup 1.0000x reference)
//
#include <hip/hip_runtime.h>
#include <hip/hip_bf16.h>

#define T_ 512
#define B_ 256
#define I_ 256
#define H_ 512

#define NG 16    // batch row-groups of 16 rows
#define NSL 2    // column slices of 256 cols

// ring: [2 slots][NG groups][NSL producers][2048 u64]; word = (h[2r],h[2r+1],tag)
#define RWORDS 2048
#define RING_BYTES (2ull * NG * NSL * RWORDS * 8)   // 1 MiB

typedef _Float16 f16x8 __attribute__((ext_vector_type(8)));
typedef float f32x4 __attribute__((ext_vector_type(4)));

__device__ __forceinline__ float tanh_fast(float v) {
  float e = __expf(2.0f * v);
  return 1.0f - 2.0f / (e + 1.0f);
}

__device__ __forceinline__ f16x8 cvt8(const float4 a, const float4 b) {
  f16x8 f;
  f[0] = (_Float16)a.x; f[1] = (_Float16)a.y; f[2] = (_Float16)a.z; f[3] = (_Float16)a.w;
  f[4] = (_Float16)b.x; f[5] = (_Float16)b.y; f[6] = (_Float16)b.z; f[7] = (_Float16)b.w;
  return f;
}

__device__ __forceinline__ unsigned long long pack2h(_Float16 a, _Float16 b, unsigned tag) {
  unsigned ua = __builtin_bit_cast(unsigned short, a);
  unsigned ub = __builtin_bit_cast(unsigned short, b);
  return (unsigned long long)(ua | (ub << 16)) | ((unsigned long long)tag << 32);
}

// -------------------------------------------------------------------------
// Persistent fused recurrence: 32 blocks x 512 threads (8 waves, 1 block/CU).
// group g = bid>>1 (rows g*16..+16); slice s = bid&1 (cols s*256..+256).
// W_hh slice [512k x 256n] (128 VGPR) + W_ih slice [256k x 256n] (64 VGPR)
// register-resident f16 B-fragments. h exchanged pairwise via self-tagged
// u64 ring words, relaxed agent atomics (no fences). Local MFMAs (x + own
// K-half of h) issue BEFORE the poll; only remote-K MFMAs wait.
// NOTE: top-of-loop __syncthreads() is REQUIRED — phase F writes hbuf's own
// half from all waves; phases B/C of the next step read it cross-wave.
// -------------------------------------------------------------------------
__global__ __launch_bounds__(512, 1) void rnn_recurrence(
    const float* __restrict__ x,      // [T,B,I]
    const float* __restrict__ w_ih,   // [H,I]
    const float* __restrict__ w_hh,   // [H,H]
    const float* __restrict__ b_ih,   // [H]
    const float* __restrict__ b_hh,   // [H]
    unsigned long long* __restrict__ ring,
    _Float16* __restrict__ hs)        // [T,B,H]; hs[t] = h_{t+1}
{
  const int tid  = threadIdx.x;
  const int lane = tid & 63;
  const int w    = tid >> 6;        // wave 0..7
  const int bid  = blockIdx.x;
  const int g    = bid >> 1;        // row group 0..15
  const int s    = bid & 1;         // col slice 0..1
  const int r0   = g * 16;
  const int c0   = s * 256;         // own col base
  const int rc0  = (s ^ 1) * 256;   // remote col base
  const int lrow = lane & 15;
  const int quad = lane >> 4;
  const int kq   = quad * 8;
  const int ktO  = s * 8;           // own-K tile range [ktO, ktO+8)
  const int ktR  = (s ^ 1) * 8;     // remote-K tile range

  __shared__ _Float16 hbuf[16][512 + 8];
  __shared__ _Float16 xbuf[2][16][256 + 8];

  // ---- weight fragments (per wave: n-tiles 2w, 2w+1 within own slice)
  f16x8 whh0[16], whh1[16];
  f16x8 wih0[8], wih1[8];
  const int n0c = c0 + (2 * w + 0) * 16 + lrow;   // global col of acc0
  const int n1c = c0 + (2 * w + 1) * 16 + lrow;   // global col of acc1
  const float bias0 = b_ih[n0c] + b_hh[n0c];
  const float bias1 = b_ih[n1c] + b_hh[n1c];
  #pragma unroll
  for (int kt = 0; kt < 16; ++kt) {
    const int k = kt * 32 + kq;
    whh0[kt] = cvt8(*(const float4*)(w_hh + (size_t)n0c * H_ + k),
                    *(const float4*)(w_hh + (size_t)n0c * H_ + k + 4));
    whh1[kt] = cvt8(*(const float4*)(w_hh + (size_t)n1c * H_ + k),
                    *(const float4*)(w_hh + (size_t)n1c * H_ + k + 4));
  }
  #pragma unroll
  for (int kt = 0; kt < 8; ++kt) {
    const int k = kt * 32 + kq;
    wih0[kt] = cvt8(*(const float4*)(w_ih + (size_t)n0c * I_ + k),
                    *(const float4*)(w_ih + (size_t)n0c * I_ + k + 4));
    wih1[kt] = cvt8(*(const float4*)(w_ih + (size_t)n1c * I_ + k),
                    *(const float4*)(w_ih + (size_t)n1c * I_ + k + 4));
  }

  // ---- init: own LDS half of h_0 = 0; stage x_0 into xbuf[0]
  {
    const int row = tid >> 5, ch = tid & 31;   // 16 rows x 32 chunks of 8
    f16x8 z = {0, 0, 0, 0, 0, 0, 0, 0};
    *(f16x8*)(&hbuf[row][c0 + ch * 8]) = z;
    const float* src = x + (size_t)(r0 + row) * I_;
    *(f16x8*)(&xbuf[0][row][ch * 8]) =
        cvt8(*(const float4*)(src + ch * 8), *(const float4*)(src + ch * 8 + 4));
  }

  for (int t = 0; t < T_; ++t) {
    const int xb = t & 1;
    __syncthreads();   // F(t-1) hbuf writes (and init) before B/C reads

    // ---- A: stage x_{t+1} (overlaps everything; consumed after next barrier)
    if (t + 1 < T_) {
      const int row = tid >> 5, ch = tid & 31;
      const float* src = x + ((size_t)(t + 1) * B_ + r0 + row) * I_;
      *(f16x8*)(&xbuf[xb ^ 1][row][ch * 8]) =
          cvt8(*(const float4*)(src + ch * 8), *(const float4*)(src + ch * 8 + 4));
    }
    // ---- B: write hs[t-1] own slice (from hbuf, coalesced)
    if (t > 0) {
      const int row = tid >> 5, ch = tid & 31;
      *(uint4*)(hs + ((size_t)(t - 1) * B_ + r0 + row) * H_ + c0 + ch * 8) =
          *(const uint4*)(&hbuf[row][c0 + ch * 8]);
    }

    // ---- C: local MFMAs — x-projection + own K-half of h (no comm needed)
    f32x4 a0a = {0.f,0.f,0.f,0.f}, a0b = {0.f,0.f,0.f,0.f};
    f32x4 a1a = {0.f,0.f,0.f,0.f}, a1b = {0.f,0.f,0.f,0.f};
    #pragma unroll
    for (int kt = 0; kt < 4; ++kt) {
      const f16x8 a = *(const f16x8*)(&xbuf[xb][lrow][kt * 32 + kq]);
      a0a = __builtin_amdgcn_mfma_f32_16x16x32_f16(a, wih0[kt], a0a, 0, 0, 0);
      a1a = __builtin_amdgcn_mfma_f32_16x16x32_f16(a, wih1[kt], a1a, 0, 0, 0);
    }
    #pragma unroll
    for (int kt = 4; kt < 8; ++kt) {
      const f16x8 a = *(const f16x8*)(&xbuf[xb][lrow][kt * 32 + kq]);
      a0b = __builtin_amdgcn_mfma_f32_16x16x32_f16(a, wih0[kt], a0b, 0, 0, 0);
      a1b = __builtin_amdgcn_mfma_f32_16x16x32_f16(a, wih1[kt], a1b, 0, 0, 0);
    }
    #pragma unroll
    for (int kk = 0; kk < 4; ++kk) {
      const int kt = ktO + kk;
      const f16x8 a = *(const f16x8*)(&hbuf[lrow][kt * 32 + kq]);
      a0a = __builtin_amdgcn_mfma_f32_16x16x32_f16(a, whh0[kt], a0a, 0, 0, 0);
      a1a = __builtin_amdgcn_mfma_f32_16x16x32_f16(a, whh1[kt], a1a, 0, 0, 0);
    }
    #pragma unroll
    for (int kk = 4; kk < 8; ++kk) {
      const int kt = ktO + kk;
      const f16x8 a = *(const f16x8*)(&hbuf[lrow][kt * 32 + kq]);
      a0b = __builtin_amdgcn_mfma_f32_16x16x32_f16(a, whh0[kt], a0b, 0, 0, 0);
      a1b = __builtin_amdgcn_mfma_f32_16x16x32_f16(a, whh1[kt], a1b, 0, 0, 0);
    }

    // ---- D: poll pair's h_t slice (4 contiguous u64/thread) + unpack to LDS
    {
      const unsigned long long* rg =
          ring + (((size_t)(t & 1) * NG + g) * NSL + (s ^ 1)) * RWORDS;
      unsigned long long v[4];
      #pragma unroll
      for (int j = 0; j < 4; ++j)
        v[j] = __hip_atomic_load(&rg[tid * 4 + j], __ATOMIC_RELAXED,
                                 __HIP_MEMORY_SCOPE_AGENT);
      int spins = 0;
      bool again = true;
      while (again) {
        again = false;
        #pragma unroll
        for (int j = 0; j < 4; ++j)
          if ((unsigned)(v[j] >> 32) != (unsigned)t) again = true;
        if (again) {
          if (spins++) __builtin_amdgcn_s_sleep(1);
          #pragma unroll
          for (int j = 0; j < 4; ++j)
            if ((unsigned)(v[j] >> 32) != (unsigned)t)
              v[j] = __hip_atomic_load(&rg[tid * 4 + j], __ATOMIC_RELAXED,
                                       __HIP_MEMORY_SCOPE_AGENT);
        }
      }
      #pragma unroll
      for (int j = 0; j < 4; ++j) {
        const int wdx = tid * 4 + j;
        const int col = rc0 + (wdx >> 3);
        const int p   = wdx & 7;
        const int r   = 4 * (p >> 1) + 2 * (p & 1);
        const unsigned lo = (unsigned)v[j];
        hbuf[r + 0][col] = __builtin_bit_cast(_Float16, (unsigned short)(lo & 0xffff));
        hbuf[r + 1][col] = __builtin_bit_cast(_Float16, (unsigned short)(lo >> 16));
      }
    }
    __syncthreads();   // remote half staged; also guards x_{t+1} staging

    // ---- E: remote-K MFMAs
    #pragma unroll
    for (int kk = 0; kk < 4; ++kk) {
      const int kt = ktR + kk;
      const f16x8 a = *(const f16x8*)(&hbuf[lrow][kt * 32 + kq]);
      a0a = __builtin_amdgcn_mfma_f32_16x16x32_f16(a, whh0[kt], a0a, 0, 0, 0);
      a1a = __builtin_amdgcn_mfma_f32_16x16x32_f16(a, whh1[kt], a1a, 0, 0, 0);
    }
    #pragma unroll
    for (int kk = 4; kk < 8; ++kk) {
      const int kt = ktR + kk;
      const f16x8 a = *(const f16x8*)(&hbuf[lrow][kt * 32 + kq]);
      a0b = __builtin_amdgcn_mfma_f32_16x16x32_f16(a, whh0[kt], a0b, 0, 0, 0);
      a1b = __builtin_amdgcn_mfma_f32_16x16x32_f16(a, whh1[kt], a1b, 0, 0, 0);
    }
    const f32x4 acc0 = a0a + a0b;
    const f32x4 acc1 = a1a + a1b;

    __syncthreads();   // all reads of h_t (local+remote) done before overwrite

    // ---- F: tanh, publish h_{t+1}: own LDS half + tagged ring words
    _Float16 e0[4], e1[4];
    #pragma unroll
    for (int r = 0; r < 4; ++r) {
      e0[r] = (_Float16)tanh_fast(acc0[r] + bias0);
      e1[r] = (_Float16)tanh_fast(acc1[r] + bias1);
      hbuf[quad * 4 + r][n0c] = e0[r];
      hbuf[quad * 4 + r][n1c] = e1[r];
    }
    {
      unsigned long long* rn =
          ring + (((size_t)((t + 1) & 1) * NG + g) * NSL + s) * RWORDS;
      const unsigned tag = (unsigned)(t + 1);
      const int o0 = (n0c - c0) * 8 + quad * 2;
      const int o1 = (n1c - c0) * 8 + quad * 2;
      __hip_atomic_store(&rn[o0 + 0], pack2h(e0[0], e0[1], tag),
                         __ATOMIC_RELAXED, __HIP_MEMORY_SCOPE_AGENT);
      __hip_atomic_store(&rn[o0 + 1], pack2h(e0[2], e0[3], tag),
                         __ATOMIC_RELAXED, __HIP_MEMORY_SCOPE_AGENT);
      __hip_atomic_store(&rn[o1 + 0], pack2h(e1[0], e1[1], tag),
                         __ATOMIC_RELAXED, __HIP_MEMORY_SCOPE_AGENT);
      __hip_atomic_store(&rn[o1 + 1], pack2h(e1[2], e1[3], tag),
                         __ATOMIC_RELAXED, __HIP_MEMORY_SCOPE_AGENT);
    }
  }

  // ---- final: hs[T-1] own slice
  __syncthreads();
  {
    const int row = tid >> 5, ch = tid & 31;
    *(uint4*)(hs + ((size_t)(T_ - 1) * B_ + r0 + row) * H_ + c0 + ch * 8) =
        *(const uint4*)(&hbuf[row][c0 + ch * 8]);
  }
}

// -------------------------------------------------------------------------
// Output head: out[m,o] = hs[m,:] @ w_fc[o,:] + b_fc[o]
// M=T*B=131072, N=256, K=512. 64x64 block tile, 4 waves in 2x2.
// -------------------------------------------------------------------------
__global__ __launch_bounds__(256) void fc_head(
    const _Float16* __restrict__ hs,  // [T*B, H]
    const float* __restrict__ w_fc,   // [I, H]
    const float* __restrict__ b_fc,   // [I]
    float* __restrict__ out)          // [T*B, I]
{
  const int tid  = threadIdx.x;
  const int lane = tid & 63;
  const int w    = tid >> 6;
  const int wm   = w & 1;
  const int wn   = w >> 1;
  const int m0   = blockIdx.x * 64;
  const int n0   = blockIdx.y * 64;
  const int lrow = lane & 15;
  const int quad = lane >> 4;
  const int kq   = quad * 8;

  __shared__ _Float16 As[64][32 + 8];
  __shared__ _Float16 Bs[64][32 + 8];

  f32x4 acc00 = {0.f,0.f,0.f,0.f}, acc01 = {0.f,0.f,0.f,0.f};
  f32x4 acc10 = {0.f,0.f,0.f,0.f}, acc11 = {0.f,0.f,0.f,0.f};

  const int srow = tid >> 2;
  const int skc  = (tid & 3) * 8;

  for (int k0 = 0; k0 < H_; k0 += 32) {
    *(uint4*)(&As[srow][skc]) =
        *(const uint4*)(hs + (size_t)(m0 + srow) * H_ + k0 + skc);
    *(f16x8*)(&Bs[srow][skc]) =
        cvt8(*(const float4*)(w_fc + (size_t)(n0 + srow) * H_ + k0 + skc),
             *(const float4*)(w_fc + (size_t)(n0 + srow) * H_ + k0 + skc + 4));
    __syncthreads();

    const f16x8 a0 = *(const f16x8*)(&As[wm * 32 + lrow][kq]);
    const f16x8 a1 = *(const f16x8*)(&As[wm * 32 + 16 + lrow][kq]);
    const f16x8 b0 = *(const f16x8*)(&Bs[wn * 32 + lrow][kq]);
    const f16x8 b1 = *(const f16x8*)(&Bs[wn * 32 + 16 + lrow][kq]);
    acc00 = __builtin_amdgcn_mfma_f32_16x16x32_f16(a0, b0, acc00, 0, 0, 0);
    acc01 = __builtin_amdgcn_mfma_f32_16x16x32_f16(a0, b1, acc01, 0, 0, 0);
    acc10 = __builtin_amdgcn_mfma_f32_16x16x32_f16(a1, b0, acc10, 0, 0, 0);
    acc11 = __builtin_amdgcn_mfma_f32_16x16x32_f16(a1, b1, acc11, 0, 0, 0);
    __syncthreads();
  }

  #pragma unroll
  for (int ni = 0; ni < 2; ++ni) {
    const int col = n0 + wn * 32 + ni * 16 + lrow;
    const float bf = b_fc[col];
    #pragma unroll
    for (int mi = 0; mi < 2; ++mi) {
      const f32x4 a = (mi == 0) ? (ni == 0 ? acc00 : acc01)
                                : (ni == 0 ? acc10 : acc11);
      #pragma unroll
      for (int r = 0; r < 4; ++r) {
        const int rowm = m0 + wm * 32 + mi * 16 + quad * 4 + r;
        out[(size_t)rowm * I_ + col] = a[r] + bf;
      }
    }
  }
}

extern "C" void kernel_launch(void* const* d_in, const int* in_sizes, int n_in,
                              void* d_out, int out_size, void* d_ws, size_t ws_size,
                              hipStream_t stream) {
  const float* x    = (const float*)d_in[0];
  const float* w_ih = (const float*)d_in[1];
  const float* w_hh = (const float*)d_in[2];
  const float* b_ih = (const float*)d_in[3];
  const float* b_hh = (const float*)d_in[4];
  const float* w_fc = (const float*)d_in[5];
  const float* b_fc = (const float*)d_in[6];
  float* out = (float*)d_out;

  unsigned long long* ring = (unsigned long long*)d_ws;
  _Float16* hs = (_Float16*)((char*)d_ws + RING_BYTES);

  // zero ring slot 0 -> (tag 0, h0 = 0); slot 1 poison tag never matches
  hipMemsetAsync(d_ws, 0, (size_t)NG * NSL * RWORDS * 8, stream);

  rnn_recurrence<<<32, 512, 0, stream>>>(x, w_ih, w_hh, b_ih, b_hh, ring, hs);
  fc_head<<<dim3(2048, 4), 256, 0, stream>>>(hs, w_fc, b_fc, out);
}